// Round 1
// baseline (601.580 us; speedup 1.0000x reference)
//
#include <hip/hip_runtime.h>
#include <hip/hip_cooperative_groups.h>
#include <math.h>

namespace cg = cooperative_groups;

#define NN 4096
#define NFEAT 512
#define NHID 60
#define NCLASS 4
#define CAP 96      // per-row nnz capacity (mean ~8.2, statistical max ~22)
#define GSTRIDE 64  // padded hidden-state row stride
#define NBLK 1024   // cooperative grid: 4 blocks/CU x 256 CU (co-resident)
#define NTHR 256
#define SCAN_IT ((NN * NN / 4) / (NBLK * NTHR))   // 16 float4s per thread

// ---- spmm edge accumulation (shared by both paths) ------------------------
__device__ __forceinline__ float spmm_row(const float* __restrict__ gin,
                                          const float* __restrict__ dcol,
                                          const int* __restrict__ cnt,
                                          const int* __restrict__ cols,
                                          const float* __restrict__ vals,
                                          int i, int lane, float di) {
    const int nn = min(cnt[i], CAP);
    float acc = gin[i * GSTRIDE + lane] * di;   // self-loop term
    const int4*   c4 = (const int4*)(cols + i * CAP);
    const float4* v4 = (const float4*)(vals + i * CAP);
    int e = 0;
    for (; e + 4 <= nn; e += 4) {
        const int4   jj = c4[e >> 2];
        const float4 vv = v4[e >> 2];
        const float f0 = vv.x * rsqrtf(1.f + dcol[jj.x]);
        const float f1 = vv.y * rsqrtf(1.f + dcol[jj.y]);
        const float f2 = vv.z * rsqrtf(1.f + dcol[jj.z]);
        const float f3 = vv.w * rsqrtf(1.f + dcol[jj.w]);
        const float g0 = gin[jj.x * GSTRIDE + lane];
        const float g1 = gin[jj.y * GSTRIDE + lane];
        const float g2 = gin[jj.z * GSTRIDE + lane];
        const float g3 = gin[jj.w * GSTRIDE + lane];
        acc = fmaf(f0, g0, fmaf(f1, g1, fmaf(f2, g2, fmaf(f3, g3, acc))));
    }
    for (; e < nn; ++e) {
        const int j = cols[i * CAP + e];
        const float f = vals[i * CAP + e] * rsqrtf(1.f + dcol[j]);
        acc = fmaf(f, gin[j * GSTRIDE + lane], acc);
    }
    return acc * di;
}

// ===========================================================================
// Fused cooperative kernel: zero -> (xw + scan) -> layer1 -> layer2 -> final
// ===========================================================================

__device__ __forceinline__ void layer_phase(const float* __restrict__ gin,
                                            float* __restrict__ gout,
                                            const float* __restrict__ dcol,
                                            const int* __restrict__ cnt,
                                            const int* __restrict__ cols,
                                            const float* __restrict__ vals,
                                            const float* __restrict__ bias,
                                            const float* __restrict__ W,
                                            float* __restrict__ smem) {
    const int w = threadIdx.x >> 6, lane = threadIdx.x & 63;
    const int i = blockIdx.x * 4 + w;               // one row per wave
    const float di = rsqrtf(1.f + dcol[i]);
    const float acc = spmm_row(gin, dcol, cnt, cols, vals, i, lane, di);
    float hv = 0.f;
    if (lane < NHID) hv = fmaxf(acc + bias[lane], 0.f);
    float* hs = smem + w * 64;                      // wave-private LDS slice
    hs[lane] = hv;
    __syncthreads();
    const int c = lane < NHID ? lane : 0;
    float o = 0.f;
    #pragma unroll 4
    for (int k = 0; k < NHID; ++k)
        o = fmaf(hs[k], W[k * NHID + c], o);        // LDS broadcast, L2-hot W
    gout[i * GSTRIDE + lane] = (lane < NHID) ? o : 0.f;
}

__device__ __forceinline__ void final_phase(const float* __restrict__ gin,
                                            float* __restrict__ out,
                                            const float* __restrict__ dcol,
                                            const int* __restrict__ cnt,
                                            const int* __restrict__ cols,
                                            const float* __restrict__ vals,
                                            const float* __restrict__ b3,
                                            const float* __restrict__ lw,
                                            const float* __restrict__ lb,
                                            float* __restrict__ smem) {
    const int w = threadIdx.x >> 6, lane = threadIdx.x & 63;
    const int i = blockIdx.x * 4 + w;
    const float di = rsqrtf(1.f + dcol[i]);
    const float acc = spmm_row(gin, dcol, cnt, cols, vals, i, lane, di);
    float* hs = smem + w * 64;
    hs[lane] = (lane < NHID) ? acc + b3[lane] : 0.f;
    __syncthreads();
    if (lane < NCLASS) {
        float o = lb[lane];
        #pragma unroll 4
        for (int k = 0; k < NHID; ++k)
            o = fmaf(hs[k], lw[k * NCLASS + lane], o);
        float m = fmaxf(o, __shfl_xor(o, 1));
        m = fmaxf(m, __shfl_xor(m, 2));
        const float ex = __expf(o - m);
        float ss = ex + __shfl_xor(ex, 1);
        ss += __shfl_xor(ss, 2);
        out[i * NCLASS + lane] = o - m - __logf(ss);
    }
}

__global__ __launch_bounds__(NTHR, 4) void k_fused(
    const float* __restrict__ x,  const float* __restrict__ adj,
    const float* __restrict__ P,  const float* __restrict__ W1,
    const float* __restrict__ b1, const float* __restrict__ W2,
    const float* __restrict__ b2, const float* __restrict__ W3,
    const float* __restrict__ b3, const float* __restrict__ lw,
    const float* __restrict__ lb, float* __restrict__ out,
    float* __restrict__ dcol, int* __restrict__ cnt,
    int* __restrict__ cols,   float* __restrict__ vals,
    float* __restrict__ bufA, float* __restrict__ bufB) {
    cg::grid_group grid = cg::this_grid();
    __shared__ float smem[1024];
    const int tid = threadIdx.x;
    const int t = blockIdx.x * NTHR + tid;

    // ---- phase 0: zero accumulators (workspace arrives poisoned) ----------
    if (t < NN) { dcol[t] = 0.f; cnt[t] = 0; }
    grid.sync();

    // ---- phase 1a: g1 = x @ W1 -> bufA (4 rows/block, K split over waves) -
    {
        const int w = tid >> 6, lane = tid & 63;
        const int c = lane < NHID ? lane : 0;
        const int row0 = blockIdx.x * 4;
        const int k0 = w * (NFEAT / 4);
        const float* x0 = x + (row0 + 0) * NFEAT;
        const float* x1 = x + (row0 + 1) * NFEAT;
        const float* x2 = x + (row0 + 2) * NFEAT;
        const float* x3 = x + (row0 + 3) * NFEAT;
        float a0 = 0.f, a1 = 0.f, a2 = 0.f, a3 = 0.f;
        for (int k = k0; k < k0 + NFEAT / 4; k += 4) {
            const float4 xv0 = *(const float4*)(x0 + k);   // wave-uniform 16B
            const float4 xv1 = *(const float4*)(x1 + k);
            const float4 xv2 = *(const float4*)(x2 + k);
            const float4 xv3 = *(const float4*)(x3 + k);
            const float w0 = W1[(k + 0) * NHID + c];       // lane-varying, L2-hot
            const float w1 = W1[(k + 1) * NHID + c];
            const float w2 = W1[(k + 2) * NHID + c];
            const float w3 = W1[(k + 3) * NHID + c];
            a0 = fmaf(xv0.x, w0, fmaf(xv0.y, w1, fmaf(xv0.z, w2, fmaf(xv0.w, w3, a0))));
            a1 = fmaf(xv1.x, w0, fmaf(xv1.y, w1, fmaf(xv1.z, w2, fmaf(xv1.w, w3, a1))));
            a2 = fmaf(xv2.x, w0, fmaf(xv2.y, w1, fmaf(xv2.z, w2, fmaf(xv2.w, w3, a2))));
            a3 = fmaf(xv3.x, w0, fmaf(xv3.y, w1, fmaf(xv3.z, w2, fmaf(xv3.w, w3, a3))));
        }
        smem[(w * 4 + 0) * 64 + lane] = a0;
        smem[(w * 4 + 1) * 64 + lane] = a1;
        smem[(w * 4 + 2) * 64 + lane] = a2;
        smem[(w * 4 + 3) * 64 + lane] = a3;
        __syncthreads();
        const float o = smem[(0 * 4 + w) * 64 + lane] + smem[(1 * 4 + w) * 64 + lane]
                      + smem[(2 * 4 + w) * 64 + lane] + smem[(3 * 4 + w) * 64 + lane];
        bufA[(row0 + w) * GSTRIDE + lane] = (lane < NHID) ? o : 0.f;
    }

    // ---- phase 1b: edge scan, grid-stride over 67 MB adjacency ------------
    {
        #pragma unroll 4
        for (int it = 0; it < SCAN_IT; ++it) {
            const int v = t + it * (NBLK * NTHR);
            const float4 a = ((const float4*)adj)[v];
            if (a.x + a.y + a.z + a.w == 0.f) continue;  // adj is 0/1
            const float av[4] = {a.x, a.y, a.z, a.w};
            const int e0 = v * 4;
            #pragma unroll
            for (int q = 0; q < 4; ++q) {
                if (av[q] != 0.f) {
                    const int e = e0 + q;
                    const int i = e >> 12;
                    const int j = e & (NN - 1);
                    const int hi = i > j ? i : j;
                    const int lo = i > j ? j : i;
                    const float pv = P[((hi * (hi + 1)) >> 1) + lo];
                    const float s = av[q] / (1.f + __expf(-pv)); // sigmoid*adj
                    atomicAdd(&dcol[j], s);
                    const int pos = atomicAdd(&cnt[i], 1);
                    if (pos < CAP) { cols[i * CAP + pos] = j; vals[i * CAP + pos] = s; }
                }
            }
        }
    }
    grid.sync();

    // ---- phases 2-4: GCN layers + classifier ------------------------------
    layer_phase(bufA, bufB, dcol, cnt, cols, vals, b1, W2, smem);
    grid.sync();
    layer_phase(bufB, bufA, dcol, cnt, cols, vals, b2, W3, smem);
    grid.sync();
    final_phase(bufA, out, dcol, cnt, cols, vals, b3, lw, lb, smem);
}

// ===========================================================================
// Fallback path (original 6-dispatch pipeline) — used only if the
// cooperative launch is rejected (e.g. unsupported under graph capture).
// ===========================================================================

__global__ __launch_bounds__(256) void k_scan(const float* __restrict__ adj,
                                              const float* __restrict__ P,
                                              float* __restrict__ dcol,
                                              int* __restrict__ cnt,
                                              int* __restrict__ cols,
                                              float* __restrict__ vals) {
    const int v = blockIdx.x * 256 + threadIdx.x;
    const float4 a = ((const float4*)adj)[v];
    if (a.x + a.y + a.z + a.w == 0.f) return;
    const float av[4] = {a.x, a.y, a.z, a.w};
    const int e0 = v * 4;
    #pragma unroll
    for (int q = 0; q < 4; ++q) {
        if (av[q] != 0.f) {
            const int e = e0 + q;
            const int i = e >> 12;
            const int j = e & (NN - 1);
            const int hi = i > j ? i : j;
            const int lo = i > j ? j : i;
            const float pv = P[((hi * (hi + 1)) >> 1) + lo];
            const float s = av[q] / (1.f + __expf(-pv));
            atomicAdd(&dcol[j], s);
            const int pos = atomicAdd(&cnt[i], 1);
            if (pos < CAP) { cols[i * CAP + pos] = j; vals[i * CAP + pos] = s; }
        }
    }
}

__global__ __launch_bounds__(256) void k_xw(const float* __restrict__ x,
                                            const float* __restrict__ W1,
                                            float* __restrict__ g1) {
    __shared__ float part[1024];
    const int tid = threadIdx.x;
    const int w = tid >> 6, lane = tid & 63;
    const int c = lane < NHID ? lane : 0;
    const int row0 = blockIdx.x * 4;
    const int k0 = w * (NFEAT / 4);
    const float* x0 = x + (row0 + 0) * NFEAT;
    const float* x1 = x + (row0 + 1) * NFEAT;
    const float* x2 = x + (row0 + 2) * NFEAT;
    const float* x3 = x + (row0 + 3) * NFEAT;
    float a0 = 0.f, a1 = 0.f, a2 = 0.f, a3 = 0.f;
    for (int k = k0; k < k0 + NFEAT / 4; k += 4) {
        const float4 xv0 = *(const float4*)(x0 + k);
        const float4 xv1 = *(const float4*)(x1 + k);
        const float4 xv2 = *(const float4*)(x2 + k);
        const float4 xv3 = *(const float4*)(x3 + k);
        const float w0 = W1[(k + 0) * NHID + c];
        const float w1 = W1[(k + 1) * NHID + c];
        const float w2 = W1[(k + 2) * NHID + c];
        const float w3 = W1[(k + 3) * NHID + c];
        a0 = fmaf(xv0.x, w0, fmaf(xv0.y, w1, fmaf(xv0.z, w2, fmaf(xv0.w, w3, a0))));
        a1 = fmaf(xv1.x, w0, fmaf(xv1.y, w1, fmaf(xv1.z, w2, fmaf(xv1.w, w3, a1))));
        a2 = fmaf(xv2.x, w0, fmaf(xv2.y, w1, fmaf(xv2.z, w2, fmaf(xv2.w, w3, a2))));
        a3 = fmaf(xv3.x, w0, fmaf(xv3.y, w1, fmaf(xv3.z, w2, fmaf(xv3.w, w3, a3))));
    }
    part[(w * 4 + 0) * 64 + lane] = a0;
    part[(w * 4 + 1) * 64 + lane] = a1;
    part[(w * 4 + 2) * 64 + lane] = a2;
    part[(w * 4 + 3) * 64 + lane] = a3;
    __syncthreads();
    const float o = part[(0 * 4 + w) * 64 + lane] + part[(1 * 4 + w) * 64 + lane]
                  + part[(2 * 4 + w) * 64 + lane] + part[(3 * 4 + w) * 64 + lane];
    g1[(row0 + w) * GSTRIDE + lane] = (lane < NHID) ? o : 0.f;
}

__global__ __launch_bounds__(64) void k_layer(const float* __restrict__ gin,
                                              float* __restrict__ gout,
                                              const float* __restrict__ dcol,
                                              const int* __restrict__ cnt,
                                              const int* __restrict__ cols,
                                              const float* __restrict__ vals,
                                              const float* __restrict__ bias,
                                              const float* __restrict__ W) {
    __shared__ float hs[64];
    const int i = blockIdx.x;
    const int lane = threadIdx.x;
    const float di = rsqrtf(1.f + dcol[i]);
    const float acc = spmm_row(gin, dcol, cnt, cols, vals, i, lane, di);
    float hv = 0.f;
    if (lane < NHID) hv = fmaxf(acc + bias[lane], 0.f);
    hs[lane] = hv;
    __syncthreads();
    const int c = lane < NHID ? lane : 0;
    float o = 0.f;
    #pragma unroll 4
    for (int k = 0; k < NHID; ++k)
        o = fmaf(hs[k], W[k * NHID + c], o);
    gout[i * GSTRIDE + lane] = (lane < NHID) ? o : 0.f;
}

__global__ __launch_bounds__(64) void k_final(const float* __restrict__ gin,
                                              float* __restrict__ out,
                                              const float* __restrict__ dcol,
                                              const int* __restrict__ cnt,
                                              const int* __restrict__ cols,
                                              const float* __restrict__ vals,
                                              const float* __restrict__ b3,
                                              const float* __restrict__ lw,
                                              const float* __restrict__ lb) {
    __shared__ float hs[64];
    const int i = blockIdx.x;
    const int lane = threadIdx.x;
    const float di = rsqrtf(1.f + dcol[i]);
    const float acc = spmm_row(gin, dcol, cnt, cols, vals, i, lane, di);
    hs[lane] = (lane < NHID) ? acc + b3[lane] : 0.f;
    __syncthreads();
    if (lane < NCLASS) {
        float o = lb[lane];
        #pragma unroll 4
        for (int k = 0; k < NHID; ++k)
            o = fmaf(hs[k], lw[k * NCLASS + lane], o);
        float m = fmaxf(o, __shfl_xor(o, 1));
        m = fmaxf(m, __shfl_xor(m, 2));
        const float ex = __expf(o - m);
        float ss = ex + __shfl_xor(ex, 1);
        ss += __shfl_xor(ss, 2);
        out[i * NCLASS + lane] = o - m - __logf(ss);
    }
}

extern "C" void kernel_launch(void* const* d_in, const int* in_sizes, int n_in,
                              void* d_out, int out_size, void* d_ws, size_t ws_size,
                              hipStream_t stream) {
    const float* x   = (const float*)d_in[0];   // 4096 x 512
    const float* adj = (const float*)d_in[1];   // 4096 x 4096
    const float* P   = (const float*)d_in[2];   // 8390656
    const float* W1  = (const float*)d_in[3];   // 512 x 60
    const float* b1  = (const float*)d_in[4];
    const float* W2  = (const float*)d_in[5];   // 60 x 60
    const float* b2  = (const float*)d_in[6];
    const float* W3  = (const float*)d_in[7];   // 60 x 60
    const float* b3  = (const float*)d_in[8];
    const float* lw  = (const float*)d_in[9];   // 60 x 4
    const float* lb  = (const float*)d_in[10];
    float* out = (float*)d_out;                 // 4096 x 4

    char* ws = (char*)d_ws;
    float* dcol = (float*)(ws);                 // 16 KiB
    int*   cnt  = (int*)(ws + 16384);           // 16 KiB
    int*   cols = (int*)(ws + 32768);                           // 1.5 MiB
    float* vals = (float*)(ws + 32768 + 1572864);               // 1.5 MiB
    float* bufA = (float*)(ws + 32768 + 2 * 1572864);           // 1 MiB
    float* bufB = (float*)(ws + 32768 + 2 * 1572864 + 1048576); // 1 MiB

    void* kp[] = { (void*)&x,  (void*)&adj, (void*)&P,  (void*)&W1, (void*)&b1,
                   (void*)&W2, (void*)&b2,  (void*)&W3, (void*)&b3, (void*)&lw,
                   (void*)&lb, (void*)&out, (void*)&dcol, (void*)&cnt,
                   (void*)&cols, (void*)&vals, (void*)&bufA, (void*)&bufB };

    hipError_t e = hipLaunchCooperativeKernel((const void*)k_fused,
                                              dim3(NBLK), dim3(NTHR),
                                              kp, 0, stream);
    if (e != hipSuccess) {
        // Fallback: original 6-dispatch pipeline (identical numerics).
        hipMemsetAsync(ws, 0, 32768, stream);
        k_scan <<<(NN * NN / 4) / 256, 256, 0, stream>>>(adj, P, dcol, cnt, cols, vals);
        k_xw   <<<NN / 4, 256, 0, stream>>>(x, W1, bufA);
        k_layer<<<NN, 64, 0, stream>>>(bufA, bufB, dcol, cnt, cols, vals, b1, W2);
        k_layer<<<NN, 64, 0, stream>>>(bufB, bufA, dcol, cnt, cols, vals, b2, W3);
        k_final<<<NN, 64, 0, stream>>>(bufA, out, dcol, cnt, cols, vals, b3, lw, lb);
    }
}

// Round 2
// 205.070 us; speedup vs baseline: 2.9335x; 2.9335x over previous
//
#include <hip/hip_runtime.h>
#include <math.h>

#define NN 4096
#define NFEAT 512
#define NHID 60
#define NCLASS 4
#define CAP 96      // per-row nnz capacity (mean ~8.2, statistical max ~22)
#define GSTRIDE 64  // padded hidden-state row stride
#define SCANBLK (NN * NN / 4 / 256)   // 16384 scan blocks (one float4/thread)
#define XWBLK (NN / 4)                // 1024 xw blocks (4 rows each)

// ---- merged: edge scan (blocks [0,16384)) + x@W1 (blocks [16384,17408)) ---
// The two halves are independent; both must simply complete before k_layer.
__global__ __launch_bounds__(256) void k_scan_xw(const float* __restrict__ x,
                                                 const float* __restrict__ adj,
                                                 const float* __restrict__ P,
                                                 const float* __restrict__ W1,
                                                 float* __restrict__ dcol,
                                                 int* __restrict__ cnt,
                                                 int* __restrict__ cols,
                                                 float* __restrict__ vals,
                                                 float* __restrict__ g1) {
    __shared__ float part[1024];
    const int tid = threadIdx.x;

    if (blockIdx.x < SCANBLK) {
        // ---- scan: one float4 of adjacency per thread -----------------
        const int v = blockIdx.x * 256 + tid;
        const float4 a = ((const float4*)adj)[v];
        if (a.x + a.y + a.z + a.w == 0.f) return;   // adj is 0/1
        const float av[4] = {a.x, a.y, a.z, a.w};
        const int e0 = v * 4;
        #pragma unroll
        for (int q = 0; q < 4; ++q) {
            if (av[q] != 0.f) {
                const int e = e0 + q;
                const int i = e >> 12;
                const int j = e & (NN - 1);
                const int hi = i > j ? i : j;
                const int lo = i > j ? j : i;
                const float pv = P[((hi * (hi + 1)) >> 1) + lo];
                const float s = av[q] / (1.f + __expf(-pv));   // sigmoid(P)*adj
                atomicAdd(&dcol[j], s);
                const int pos = atomicAdd(&cnt[i], 1);
                if (pos < CAP) { cols[i * CAP + pos] = j; vals[i * CAP + pos] = s; }
            }
        }
        return;
    }

    // ---- x @ W1: 4 rows/block, K split over 4 waves -------------------
    const int w = tid >> 6, lane = tid & 63;
    const int c = lane < NHID ? lane : 0;
    const int row0 = (blockIdx.x - SCANBLK) * 4;
    const int k0 = w * (NFEAT / 4);
    const float* x0 = x + (row0 + 0) * NFEAT;
    const float* x1 = x + (row0 + 1) * NFEAT;
    const float* x2 = x + (row0 + 2) * NFEAT;
    const float* x3 = x + (row0 + 3) * NFEAT;
    float a0 = 0.f, a1 = 0.f, a2 = 0.f, a3 = 0.f;
    for (int k = k0; k < k0 + NFEAT / 4; k += 4) {
        const float4 xv0 = *(const float4*)(x0 + k);   // wave-uniform 16B
        const float4 xv1 = *(const float4*)(x1 + k);
        const float4 xv2 = *(const float4*)(x2 + k);
        const float4 xv3 = *(const float4*)(x3 + k);
        const float w0 = W1[(k + 0) * NHID + c];       // lane-varying, L2-hot
        const float w1 = W1[(k + 1) * NHID + c];
        const float w2 = W1[(k + 2) * NHID + c];
        const float w3 = W1[(k + 3) * NHID + c];
        a0 = fmaf(xv0.x, w0, fmaf(xv0.y, w1, fmaf(xv0.z, w2, fmaf(xv0.w, w3, a0))));
        a1 = fmaf(xv1.x, w0, fmaf(xv1.y, w1, fmaf(xv1.z, w2, fmaf(xv1.w, w3, a1))));
        a2 = fmaf(xv2.x, w0, fmaf(xv2.y, w1, fmaf(xv2.z, w2, fmaf(xv2.w, w3, a2))));
        a3 = fmaf(xv3.x, w0, fmaf(xv3.y, w1, fmaf(xv3.z, w2, fmaf(xv3.w, w3, a3))));
    }
    part[(w * 4 + 0) * 64 + lane] = a0;
    part[(w * 4 + 1) * 64 + lane] = a1;
    part[(w * 4 + 2) * 64 + lane] = a2;
    part[(w * 4 + 3) * 64 + lane] = a3;
    __syncthreads();
    // wave w reduces row w across the 4 K-slices
    const float o = part[(0 * 4 + w) * 64 + lane] + part[(1 * 4 + w) * 64 + lane]
                  + part[(2 * 4 + w) * 64 + lane] + part[(3 * 4 + w) * 64 + lane];
    g1[(row0 + w) * GSTRIDE + lane] = (lane < NHID) ? o : 0.f;
}

// ---- spmm edge accumulation, 4-batched for MLP ----------------------------
__device__ __forceinline__ float spmm_row(const float* __restrict__ gin,
                                          const float* __restrict__ dcol,
                                          const int* __restrict__ cnt,
                                          const int* __restrict__ cols,
                                          const float* __restrict__ vals,
                                          int i, int lane, float di) {
    const int nn = min(cnt[i], CAP);
    float acc = gin[i * GSTRIDE + lane] * di;   // self-loop term
    const int4*   c4 = (const int4*)(cols + i * CAP);
    const float4* v4 = (const float4*)(vals + i * CAP);
    int e = 0;
    for (; e + 4 <= nn; e += 4) {
        const int4   jj = c4[e >> 2];
        const float4 vv = v4[e >> 2];
        const float f0 = vv.x * rsqrtf(1.f + dcol[jj.x]);
        const float f1 = vv.y * rsqrtf(1.f + dcol[jj.y]);
        const float f2 = vv.z * rsqrtf(1.f + dcol[jj.z]);
        const float f3 = vv.w * rsqrtf(1.f + dcol[jj.w]);
        const float g0 = gin[jj.x * GSTRIDE + lane];
        const float g1 = gin[jj.y * GSTRIDE + lane];
        const float g2 = gin[jj.z * GSTRIDE + lane];
        const float g3 = gin[jj.w * GSTRIDE + lane];
        acc = fmaf(f0, g0, fmaf(f1, g1, fmaf(f2, g2, fmaf(f3, g3, acc))));
    }
    for (; e < nn; ++e) {
        const int j = cols[i * CAP + e];
        const float f = vals[i * CAP + e] * rsqrtf(1.f + dcol[j]);
        acc = fmaf(f, gin[j * GSTRIDE + lane], acc);
    }
    return acc * di;
}

// ---- h = relu(spmm(gin)+bias); gout = h @ W. 4 rows/block, W in LDS. ------
__global__ __launch_bounds__(256) void k_layer(const float* __restrict__ gin,
                                               float* __restrict__ gout,
                                               const float* __restrict__ dcol,
                                               const int* __restrict__ cnt,
                                               const int* __restrict__ cols,
                                               const float* __restrict__ vals,
                                               const float* __restrict__ bias,
                                               const float* __restrict__ W) {
    __shared__ float Ws[NHID * NHID];   // 14.4 KB, loaded once per block
    __shared__ float hs[256];
    const int tid = threadIdx.x;
    for (int t = tid; t < NHID * NHID; t += 256) Ws[t] = W[t];
    const int w = tid >> 6, lane = tid & 63;
    const int i = blockIdx.x * 4 + w;               // one row per wave
    const float di = rsqrtf(1.f + dcol[i]);
    const float acc = spmm_row(gin, dcol, cnt, cols, vals, i, lane, di);
    hs[w * 64 + lane] = (lane < NHID) ? fmaxf(acc + bias[lane], 0.f) : 0.f;
    __syncthreads();                                // covers Ws + hs stores
    const int c = lane < NHID ? lane : 0;
    float o = 0.f;
    #pragma unroll 6
    for (int k = 0; k < NHID; ++k)
        o = fmaf(hs[w * 64 + k], Ws[k * NHID + c], o);  // broadcast + 2/bank (free)
    gout[i * GSTRIDE + lane] = (lane < NHID) ? o : 0.f;
}

// ---- h3 = spmm+b3; logits = h3@lin_w+lin_b; log_softmax. 4 rows/block. ----
__global__ __launch_bounds__(256) void k_final(const float* __restrict__ gin,
                                               float* __restrict__ out,
                                               const float* __restrict__ dcol,
                                               const int* __restrict__ cnt,
                                               const int* __restrict__ cols,
                                               const float* __restrict__ vals,
                                               const float* __restrict__ b3,
                                               const float* __restrict__ lw,
                                               const float* __restrict__ lb) {
    __shared__ float lws[NHID * NCLASS];  // 240 floats
    __shared__ float hs[256];
    const int tid = threadIdx.x;
    for (int t = tid; t < NHID * NCLASS; t += 256) lws[t] = lw[t];
    const int w = tid >> 6, lane = tid & 63;
    const int i = blockIdx.x * 4 + w;
    const float di = rsqrtf(1.f + dcol[i]);
    const float acc = spmm_row(gin, dcol, cnt, cols, vals, i, lane, di);
    hs[w * 64 + lane] = (lane < NHID) ? acc + b3[lane] : 0.f;
    __syncthreads();
    if (lane < NCLASS) {
        float o = lb[lane];
        #pragma unroll 4
        for (int k = 0; k < NHID; ++k)
            o = fmaf(hs[w * 64 + k], lws[k * NCLASS + lane], o);
        float m = fmaxf(o, __shfl_xor(o, 1));
        m = fmaxf(m, __shfl_xor(m, 2));
        const float ex = __expf(o - m);
        float ss = ex + __shfl_xor(ex, 1);
        ss += __shfl_xor(ss, 2);
        out[i * NCLASS + lane] = o - m - __logf(ss);
    }
}

extern "C" void kernel_launch(void* const* d_in, const int* in_sizes, int n_in,
                              void* d_out, int out_size, void* d_ws, size_t ws_size,
                              hipStream_t stream) {
    const float* x   = (const float*)d_in[0];   // 4096 x 512
    const float* adj = (const float*)d_in[1];   // 4096 x 4096
    const float* P   = (const float*)d_in[2];   // 8390656
    const float* W1  = (const float*)d_in[3];   // 512 x 60
    const float* b1  = (const float*)d_in[4];
    const float* W2  = (const float*)d_in[5];   // 60 x 60
    const float* b2  = (const float*)d_in[6];
    const float* W3  = (const float*)d_in[7];   // 60 x 60
    const float* b3  = (const float*)d_in[8];
    const float* lw  = (const float*)d_in[9];   // 60 x 4
    const float* lb  = (const float*)d_in[10];
    float* out = (float*)d_out;                 // 4096 x 4

    char* ws = (char*)d_ws;
    float* dcol = (float*)(ws);                 // 16 KiB (zeroed)
    int*   cnt  = (int*)(ws + 16384);           // 16 KiB (zeroed)
    int*   cols = (int*)(ws + 32768);                           // 1.5 MiB
    float* vals = (float*)(ws + 32768 + 1572864);               // 1.5 MiB
    float* bufA = (float*)(ws + 32768 + 2 * 1572864);           // 1 MiB
    float* bufB = (float*)(ws + 32768 + 2 * 1572864 + 1048576); // 1 MiB

    hipMemsetAsync(ws, 0, 32768, stream);       // zero dcol + cnt

    k_scan_xw<<<SCANBLK + XWBLK, 256, 0, stream>>>(x, adj, P, W1,
                                                   dcol, cnt, cols, vals, bufA);
    k_layer<<<NN / 4, 256, 0, stream>>>(bufA, bufB, dcol, cnt, cols, vals, b1, W2);
    k_layer<<<NN / 4, 256, 0, stream>>>(bufB, bufA, dcol, cnt, cols, vals, b2, W3);
    k_final<<<NN / 4, 256, 0, stream>>>(bufA, out, dcol, cnt, cols, vals, b3, lw, lb);
}

// Round 3
// 193.659 us; speedup vs baseline: 3.1064x; 1.0589x over previous
//
#include <hip/hip_runtime.h>
#include <math.h>

#define NN 4096
#define NFEAT 512
#define NHID 60
#define NCLASS 4
#define CAP 96      // per-row nnz capacity (mean ~8.2, statistical max ~22)
#define GSTRIDE 64  // padded hidden-state row stride

// ---- scan sub_adj -> per-row lists + column sums --------------------------
// 4096 blocks x 256 threads x 4 float4s: 4 KB in flight per wave (4x MLP).
__global__ __launch_bounds__(256) void k_scan(const float* __restrict__ adj,
                                              const float* __restrict__ P,
                                              float* __restrict__ dcol,
                                              int* __restrict__ cnt,
                                              int* __restrict__ cols,
                                              float* __restrict__ vals) {
    const int base = blockIdx.x * 1024 + threadIdx.x;   // float4 index
    const float4* adj4 = (const float4*)adj;
    // 4 independent loads issued before any use -> 4 outstanding vmem ops
    const float4 a0 = adj4[base];
    const float4 a1 = adj4[base + 256];
    const float4 a2 = adj4[base + 512];
    const float4 a3 = adj4[base + 768];
    // adj elements are 0.0f or 1.0f -> combined sum is an any-nonzero test
    const float s01 = (a0.x + a0.y + a0.z + a0.w) + (a1.x + a1.y + a1.z + a1.w);
    const float s23 = (a2.x + a2.y + a2.z + a2.w) + (a3.x + a3.y + a3.z + a3.w);
    if (s01 + s23 == 0.f) return;                       // ~97% of threads
    const float4 aa[4] = {a0, a1, a2, a3};
    #pragma unroll
    for (int u = 0; u < 4; ++u) {
        const float4 a = aa[u];
        if (a.x + a.y + a.z + a.w == 0.f) continue;
        const float av[4] = {a.x, a.y, a.z, a.w};
        const int e0 = (base + u * 256) * 4;
        #pragma unroll
        for (int q = 0; q < 4; ++q) {
            if (av[q] != 0.f) {
                const int e = e0 + q;
                const int i = e >> 12;
                const int j = e & (NN - 1);
                const int hi = i > j ? i : j;
                const int lo = i > j ? j : i;
                const float pv = P[((hi * (hi + 1)) >> 1) + lo];
                const float s = av[q] / (1.f + __expf(-pv));   // sigmoid(P) * adj
                atomicAdd(&dcol[j], s);
                const int pos = atomicAdd(&cnt[i], 1);
                if (pos < CAP) { cols[i * CAP + pos] = j; vals[i * CAP + pos] = s; }
            }
        }
    }
}

// ---- G1 = x @ W1 (4096x512 @ 512x60): 4 rows/block, K split over 4 waves --
__global__ __launch_bounds__(256) void k_xw(const float* __restrict__ x,
                                            const float* __restrict__ W1,
                                            float* __restrict__ g1) {
    __shared__ float part[1024];
    const int tid = threadIdx.x;
    const int w = tid >> 6, lane = tid & 63;
    const int c = lane < NHID ? lane : 0;
    const int row0 = blockIdx.x * 4;
    const int k0 = w * (NFEAT / 4);
    const float* x0 = x + (row0 + 0) * NFEAT;
    const float* x1 = x + (row0 + 1) * NFEAT;
    const float* x2 = x + (row0 + 2) * NFEAT;
    const float* x3 = x + (row0 + 3) * NFEAT;
    float a0 = 0.f, a1 = 0.f, a2 = 0.f, a3 = 0.f;
    for (int k = k0; k < k0 + NFEAT / 4; k += 4) {
        const float4 xv0 = *(const float4*)(x0 + k);   // wave-uniform 16B
        const float4 xv1 = *(const float4*)(x1 + k);
        const float4 xv2 = *(const float4*)(x2 + k);
        const float4 xv3 = *(const float4*)(x3 + k);
        const float w0 = W1[(k + 0) * NHID + c];       // lane-varying, L2-hot
        const float w1 = W1[(k + 1) * NHID + c];
        const float w2 = W1[(k + 2) * NHID + c];
        const float w3 = W1[(k + 3) * NHID + c];
        a0 = fmaf(xv0.x, w0, fmaf(xv0.y, w1, fmaf(xv0.z, w2, fmaf(xv0.w, w3, a0))));
        a1 = fmaf(xv1.x, w0, fmaf(xv1.y, w1, fmaf(xv1.z, w2, fmaf(xv1.w, w3, a1))));
        a2 = fmaf(xv2.x, w0, fmaf(xv2.y, w1, fmaf(xv2.z, w2, fmaf(xv2.w, w3, a2))));
        a3 = fmaf(xv3.x, w0, fmaf(xv3.y, w1, fmaf(xv3.z, w2, fmaf(xv3.w, w3, a3))));
    }
    part[(w * 4 + 0) * 64 + lane] = a0;
    part[(w * 4 + 1) * 64 + lane] = a1;
    part[(w * 4 + 2) * 64 + lane] = a2;
    part[(w * 4 + 3) * 64 + lane] = a3;
    __syncthreads();
    // wave w reduces row w across the 4 K-slices
    const float o = part[(0 * 4 + w) * 64 + lane] + part[(1 * 4 + w) * 64 + lane]
                  + part[(2 * 4 + w) * 64 + lane] + part[(3 * 4 + w) * 64 + lane];
    g1[(row0 + w) * GSTRIDE + lane] = (lane < NHID) ? o : 0.f;
}

// ---- spmm edge accumulation, 4-batched for MLP ----------------------------
__device__ __forceinline__ float spmm_row(const float* __restrict__ gin,
                                          const float* __restrict__ dcol,
                                          const int* __restrict__ cnt,
                                          const int* __restrict__ cols,
                                          const float* __restrict__ vals,
                                          int i, int lane, float di) {
    const int nn = min(cnt[i], CAP);
    float acc = gin[i * GSTRIDE + lane] * di;   // self-loop term
    const int4*   c4 = (const int4*)(cols + i * CAP);
    const float4* v4 = (const float4*)(vals + i * CAP);
    int e = 0;
    for (; e + 4 <= nn; e += 4) {
        const int4   jj = c4[e >> 2];
        const float4 vv = v4[e >> 2];
        const float f0 = vv.x * rsqrtf(1.f + dcol[jj.x]);
        const float f1 = vv.y * rsqrtf(1.f + dcol[jj.y]);
        const float f2 = vv.z * rsqrtf(1.f + dcol[jj.z]);
        const float f3 = vv.w * rsqrtf(1.f + dcol[jj.w]);
        const float g0 = gin[jj.x * GSTRIDE + lane];
        const float g1 = gin[jj.y * GSTRIDE + lane];
        const float g2 = gin[jj.z * GSTRIDE + lane];
        const float g3 = gin[jj.w * GSTRIDE + lane];
        acc = fmaf(f0, g0, fmaf(f1, g1, fmaf(f2, g2, fmaf(f3, g3, acc))));
    }
    for (; e < nn; ++e) {
        const int j = cols[i * CAP + e];
        const float f = vals[i * CAP + e] * rsqrtf(1.f + dcol[j]);
        acc = fmaf(f, gin[j * GSTRIDE + lane], acc);
    }
    return acc * di;
}

// ---- h = relu(spmm(gin)+bias); gout = h @ W. 4 rows/block, W in LDS. ------
__global__ __launch_bounds__(256) void k_layer(const float* __restrict__ gin,
                                               float* __restrict__ gout,
                                               const float* __restrict__ dcol,
                                               const int* __restrict__ cnt,
                                               const int* __restrict__ cols,
                                               const float* __restrict__ vals,
                                               const float* __restrict__ bias,
                                               const float* __restrict__ W) {
    __shared__ float Ws[NHID * NHID];   // 14.4 KB, loaded once per block
    __shared__ float hs[256];
    const int tid = threadIdx.x;
    for (int t = tid; t < NHID * NHID; t += 256) Ws[t] = W[t];
    const int w = tid >> 6, lane = tid & 63;
    const int i = blockIdx.x * 4 + w;               // one row per wave
    const float di = rsqrtf(1.f + dcol[i]);
    const float acc = spmm_row(gin, dcol, cnt, cols, vals, i, lane, di);
    hs[w * 64 + lane] = (lane < NHID) ? fmaxf(acc + bias[lane], 0.f) : 0.f;
    __syncthreads();                                // covers Ws + hs stores
    const int c = lane < NHID ? lane : 0;
    float o = 0.f;
    #pragma unroll 6
    for (int k = 0; k < NHID; ++k)
        o = fmaf(hs[w * 64 + k], Ws[k * NHID + c], o);  // broadcast + 2/bank (free)
    gout[i * GSTRIDE + lane] = (lane < NHID) ? o : 0.f;
}

// ---- h3 = spmm+b3; logits = h3@lin_w+lin_b; log_softmax. 4 rows/block. ----
__global__ __launch_bounds__(256) void k_final(const float* __restrict__ gin,
                                               float* __restrict__ out,
                                               const float* __restrict__ dcol,
                                               const int* __restrict__ cnt,
                                               const int* __restrict__ cols,
                                               const float* __restrict__ vals,
                                               const float* __restrict__ b3,
                                               const float* __restrict__ lw,
                                               const float* __restrict__ lb) {
    __shared__ float lws[NHID * NCLASS];  // 240 floats
    __shared__ float hs[256];
    const int tid = threadIdx.x;
    for (int t = tid; t < NHID * NCLASS; t += 256) lws[t] = lw[t];
    const int w = tid >> 6, lane = tid & 63;
    const int i = blockIdx.x * 4 + w;
    const float di = rsqrtf(1.f + dcol[i]);
    const float acc = spmm_row(gin, dcol, cnt, cols, vals, i, lane, di);
    hs[w * 64 + lane] = (lane < NHID) ? acc + b3[lane] : 0.f;
    __syncthreads();
    if (lane < NCLASS) {
        float o = lb[lane];
        #pragma unroll 4
        for (int k = 0; k < NHID; ++k)
            o = fmaf(hs[w * 64 + k], lws[k * NCLASS + lane], o);
        float m = fmaxf(o, __shfl_xor(o, 1));
        m = fmaxf(m, __shfl_xor(m, 2));
        const float ex = __expf(o - m);
        float ss = ex + __shfl_xor(ex, 1);
        ss += __shfl_xor(ss, 2);
        out[i * NCLASS + lane] = o - m - __logf(ss);
    }
}

extern "C" void kernel_launch(void* const* d_in, const int* in_sizes, int n_in,
                              void* d_out, int out_size, void* d_ws, size_t ws_size,
                              hipStream_t stream) {
    const float* x   = (const float*)d_in[0];   // 4096 x 512
    const float* adj = (const float*)d_in[1];   // 4096 x 4096
    const float* P   = (const float*)d_in[2];   // 8390656
    const float* W1  = (const float*)d_in[3];   // 512 x 60
    const float* b1  = (const float*)d_in[4];
    const float* W2  = (const float*)d_in[5];   // 60 x 60
    const float* b2  = (const float*)d_in[6];
    const float* W3  = (const float*)d_in[7];   // 60 x 60
    const float* b3  = (const float*)d_in[8];
    const float* lw  = (const float*)d_in[9];   // 60 x 4
    const float* lb  = (const float*)d_in[10];
    float* out = (float*)d_out;                 // 4096 x 4

    char* ws = (char*)d_ws;
    float* dcol = (float*)(ws);                 // 16 KiB (zeroed)
    int*   cnt  = (int*)(ws + 16384);           // 16 KiB (zeroed)
    int*   cols = (int*)(ws + 32768);                           // 1.5 MiB
    float* vals = (float*)(ws + 32768 + 1572864);               // 1.5 MiB
    float* bufA = (float*)(ws + 32768 + 2 * 1572864);           // 1 MiB
    float* bufB = (float*)(ws + 32768 + 2 * 1572864 + 1048576); // 1 MiB

    hipMemsetAsync(ws, 0, 32768, stream);       // zero dcol + cnt

    k_scan <<<NN * NN / 4 / 1024, 256, 0, stream>>>(adj, P, dcol, cnt, cols, vals);
    k_xw   <<<NN / 4, 256, 0, stream>>>(x, W1, bufA);
    k_layer<<<NN / 4, 256, 0, stream>>>(bufA, bufB, dcol, cnt, cols, vals, b1, W2);
    k_layer<<<NN / 4, 256, 0, stream>>>(bufB, bufA, dcol, cnt, cols, vals, b2, W3);
    k_final<<<NN / 4, 256, 0, stream>>>(bufA, out, dcol, cnt, cols, vals, b3, lw, lb);
}